// Round 13
// baseline (392.250 us; speedup 1.0000x reference)
//
#include <hip/hip_runtime.h>
#include <math.h>

#define B_ 256
#define T_ 512
#define D_ 300
#define U_ 64
#define C_ 45

typedef _Float16 half_t;
typedef __attribute__((ext_vector_type(2))) _Float16 f16x2;
typedef __attribute__((ext_vector_type(8))) _Float16 f16x8;
typedef __attribute__((ext_vector_type(4))) float f32x4;
typedef __attribute__((ext_vector_type(2))) float f32x2;

// K padded 300 -> 320 (10 MFMA K-steps of 32). 12 N-tiles of 16 cols (192).
#define KSTEPS 10
#define NTILES 12

#if __has_builtin(__builtin_amdgcn_rcpf)
#define FRCP(x) __builtin_amdgcn_rcpf(x)
#else
#define FRCP(x) (1.0f / (x))
#endif

static __device__ inline float fdot2_(f16x2 a, f16x2 b, float c) {
#if __has_builtin(__builtin_amdgcn_fdot2)
    return __builtin_amdgcn_fdot2(a, b, c, false);   // v_dot2_f32_f16
#else
    return fmaf((float)a.x, (float)b.x, fmaf((float)a.y, (float)b.y, c));
#endif
}

// Guaranteed packed fp32 FMA (2 full-precision FMAs per instruction).
// R4's __builtin_elementwise_fma path was suspected to scalarize; inline asm
// removes that uncertainty.
static __device__ inline f32x2 pkfma_(f32x2 a, f32x2 b, f32x2 c) {
    f32x2 d;
    asm("v_pk_fma_f32 %0, %1, %2, %3" : "=v"(d) : "v"(a), "v"(b), "v"(c));
    return d;
}

// ---------------------------------------------------------------------------
// prep: build fragment-ready transposed w in fp16 hi/lo split (unchanged).
// ---------------------------------------------------------------------------
__global__ __launch_bounds__(256) void prep_kernel(
    const float* __restrict__ w,     // [300, 192]
    half_t* __restrict__ wt_hi,      // [7680*8]
    half_t* __restrict__ wt_lo)      // [7680*8]
{
    const int idx = blockIdx.x * 256 + threadIdx.x;
    if (idx >= KSTEPS * NTILES * 64) return;
    const int l  = idx & 63;
    const int nt = (idx >> 6) % NTILES;
    const int ks = idx / (64 * NTILES);
    const int col   = nt * 16 + (l & 15);
    const int kbase = ks * 32 + (l >> 4) * 8;

    half_t hi[8], lo[8];
#pragma unroll
    for (int e = 0; e < 8; ++e) {
        const int k = kbase + e;
        const float v = (k < D_) ? w[(size_t)k * 192 + col] : 0.f;
        const half_t h = (half_t)v;
        hi[e] = h;
        lo[e] = (half_t)(v - (float)h);
    }
    *(f16x8*)(wt_hi + (size_t)idx * 8) = *(const f16x8*)hi;
    *(f16x8*)(wt_lo + (size_t)idx * 8) = *(const f16x8*)lo;
}

// ---------------------------------------------------------------------------
// Kernel 1 (retained, no longer launched): MFMA projection — context anchor.
// ---------------------------------------------------------------------------
__global__ __launch_bounds__(256, 4) void proj_kernel(
    const float*  __restrict__ x,      // [M, 300]
    const half_t* __restrict__ wt_hi,
    const half_t* __restrict__ wt_lo,
    const float*  __restrict__ bias,   // [2, 192], row 0 = input bias
    float* __restrict__ mx)            // [M, 192]
{
    const int tid  = threadIdx.x;
    const int l    = tid & 63;
    const int wv   = tid >> 6;          // 0..3
    const int lrow = l & 15;
    const int g    = l >> 4;            // 0..3 (k-group)
    const int m0   = blockIdx.x * 64;

    f32x4 acc[4][3];
#pragma unroll
    for (int ni = 0; ni < 3; ++ni) {
        const float b = bias[wv * 48 + ni * 16 + lrow];
        const f32x4 bv = {b, b, b, b};
#pragma unroll
        for (int mi = 0; mi < 4; ++mi) acc[mi][ni] = bv;
    }

    for (int ks = 0; ks < KSTEPS; ++ks) {
        f16x8 bhi[3], blo[3];
#pragma unroll
        for (int ni = 0; ni < 3; ++ni) {
            const size_t off = ((size_t)(ks * NTILES + wv * 3 + ni) * 64 + l) * 8;
            bhi[ni] = *(const f16x8*)(wt_hi + off);
            blo[ni] = *(const f16x8*)(wt_lo + off);
        }
#pragma unroll
        for (int mi = 0; mi < 4; ++mi) {
            const float* xr = x + (size_t)(m0 + mi * 16 + lrow) * D_ + ks * 32 + g * 8;
            float xv[8];
            if (ks < 9) {
                const float4 v0 = ((const float4*)xr)[0];
                const float4 v1 = ((const float4*)xr)[1];
                xv[0] = v0.x; xv[1] = v0.y; xv[2] = v0.z; xv[3] = v0.w;
                xv[4] = v1.x; xv[5] = v1.y; xv[6] = v1.z; xv[7] = v1.w;
            } else {
                const int kb = 288 + g * 8;   // predicated tail (k in [288,320))
#pragma unroll
                for (int e = 0; e < 8; ++e) xv[e] = (kb + e < D_) ? xr[e] : 0.f;
            }
            f16x8 ahi, alo;
#pragma unroll
            for (int e = 0; e < 8; ++e) {
                const half_t h = (half_t)xv[e];
                ahi[e] = h;
                alo[e] = (half_t)(xv[e] - (float)h);
            }
#pragma unroll
            for (int ni = 0; ni < 3; ++ni) {
                acc[mi][ni] = __builtin_amdgcn_mfma_f32_16x16x32_f16(ahi, bhi[ni], acc[mi][ni], 0, 0, 0);
                acc[mi][ni] = __builtin_amdgcn_mfma_f32_16x16x32_f16(alo, bhi[ni], acc[mi][ni], 0, 0, 0);
                acc[mi][ni] = __builtin_amdgcn_mfma_f32_16x16x32_f16(ahi, blo[ni], acc[mi][ni], 0, 0, 0);
            }
        }
    }

#pragma unroll
    for (int mi = 0; mi < 4; ++mi) {
        const int rbase = m0 + mi * 16 + g * 4;
#pragma unroll
        for (int ni = 0; ni < 3; ++ni) {
            const int col = wv * 48 + ni * 16 + lrow;
#pragma unroll
            for (int r = 0; r < 4; ++r)
                mx[(size_t)(rbase + r) * 192 + col] = acc[mi][ni][r];
        }
    }
}

// ---------------------------------------------------------------------------
// Kernel 2 (retained, no longer launched): R5 scan — context anchor.
// ---------------------------------------------------------------------------
__global__ __launch_bounds__(64) void scan_kernel(
    const float* __restrict__ mx,    // [B, T, 192]
    const float* __restrict__ rk,    // [64, 192]
    const float* __restrict__ bias,  // [2, 192], row 1 = recurrent bias
    float* __restrict__ hs)          // [B, T, 64]
{
    __shared__ _Float16 hbuf[64];    // 128 B
    const int j = threadIdx.x;       // 0..63
    const int b = blockIdx.x;

    f16x2 Rz[32], Rr[32], Rh[32];
#pragma unroll
    for (int p = 0; p < 32; ++p) {
        Rz[p] = f16x2{(_Float16)rk[(size_t)(2 * p) * 192 + j],
                      (_Float16)rk[(size_t)(2 * p + 1) * 192 + j]};
        Rr[p] = f16x2{(_Float16)rk[(size_t)(2 * p) * 192 + 64 + j],
                      (_Float16)rk[(size_t)(2 * p + 1) * 192 + 64 + j]};
        Rh[p] = f16x2{(_Float16)rk[(size_t)(2 * p) * 192 + 128 + j],
                      (_Float16)rk[(size_t)(2 * p + 1) * 192 + 128 + j]};
    }
    const float rbz = bias[192 + j];
    const float rbr = bias[192 + 64 + j];
    const float rbh = bias[192 + 128 + j];

    hbuf[j] = (_Float16)0.f;
    float hj = 0.f;

    const float* mxb = mx + (size_t)b * T_ * 192 + j;
    float* hsb = hs + (size_t)b * T_ * 64 + j;

    float zb[4], rbv[4], qb[4];
#pragma unroll
    for (int i = 0; i < 4; ++i) {
        const float* p = mxb + (size_t)i * 192;
        zb[i] = p[0]; rbv[i] = p[64]; qb[i] = p[128];
    }

    union H8 { f16x8 v; f16x2 p[4]; };

    for (int t0 = 0; t0 < T_; t0 += 4) {
#pragma unroll
        for (int i = 0; i < 4; ++i) {
            const int t = t0 + i;
            const float xz = zb[i], xr = rbv[i], xh = qb[i];
            {
                const int tp = (t + 4 < T_) ? (t + 4) : (T_ - 1);
                const float* pf = mxb + (size_t)tp * 192;
                zb[i] = pf[0]; rbv[i] = pf[64]; qb[i] = pf[128];
            }
            H8 hv[8];
            const f16x8* h8 = (const f16x8*)hbuf;
#pragma unroll
            for (int q = 0; q < 8; ++q) hv[q].v = h8[q];

            float az[4] = {rbz, 0.f, 0.f, 0.f};
            float ar[4] = {rbr, 0.f, 0.f, 0.f};
            float ah[4] = {rbh, 0.f, 0.f, 0.f};
#pragma unroll
            for (int p = 0; p < 32; ++p) {
                const f16x2 hp = hv[p >> 2].p[p & 3];
                az[p & 3] = fdot2_(hp, Rz[p], az[p & 3]);
                ar[p & 3] = fdot2_(hp, Rr[p], ar[p & 3]);
                ah[p & 3] = fdot2_(hp, Rh[p], ah[p & 3]);
            }
            const float miz = (az[0] + az[1]) + (az[2] + az[3]);
            const float mir = (ar[0] + ar[1]) + (ar[2] + ar[3]);
            const float mih = (ah[0] + ah[1]) + (ah[2] + ah[3]);

            const float zg = FRCP(1.f + __expf(-(xz + miz)));
            const float rg = FRCP(1.f + __expf(-(xr + mir)));
            const float hh = fmaxf(fmaf(rg, mih, xh), 0.f);
            const float hn = fmaf(zg, hj - hh, hh);

            hbuf[j] = (_Float16)hn;
            hj = hn;
            hsb[(size_t)t * 64] = hn;
        }
    }
}

// ---------------------------------------------------------------------------
// Kernel 3: MFMA head reading f32 hs (unchanged).
// ---------------------------------------------------------------------------
__global__ __launch_bounds__(256) void head_kernel(
    const float* __restrict__ hs,     // [M, 64] f32
    const half_t* __restrict__ dwt,   // [2][3][64][8] f16 frags
    const float* __restrict__ db,     // [45]
    float* __restrict__ out)          // [M, 45]
{
    const int l    = threadIdx.x & 63;
    const int wv   = threadIdx.x >> 6;
    const int lrow = l & 15;
    const int g    = l >> 4;

    f16x8 bf[2][3];
#pragma unroll
    for (int ks2 = 0; ks2 < 2; ++ks2)
#pragma unroll
        for (int nt = 0; nt < 3; ++nt)
            bf[ks2][nt] = *(const f16x8*)(dwt + (size_t)((ks2 * 3 + nt) * 64 + l) * 8);
    float dbl[3];
#pragma unroll
    for (int nt = 0; nt < 3; ++nt) {
        const int col = nt * 16 + lrow;
        dbl[nt] = (col < C_) ? db[col] : 0.f;
    }

    const int gw = blockIdx.x * 4 + wv;
    const int nw = gridDim.x * 4;
    const int NTILE_M = (B_ * T_) / 16;   // 8192
    for (int tile = gw; tile < NTILE_M; tile += nw) {
        const int m0 = tile * 16;
        const float* ar = hs + (size_t)(m0 + lrow) * 64 + g * 8;
        const float4 v0 = ((const float4*)ar)[0];
        const float4 v1 = ((const float4*)ar)[1];
        const float4 v2 = ((const float4*)(ar + 32))[0];
        const float4 v3 = ((const float4*)(ar + 32))[1];
        f16x8 a0, a1;
        a0[0] = (_Float16)v0.x; a0[1] = (_Float16)v0.y; a0[2] = (_Float16)v0.z; a0[3] = (_Float16)v0.w;
        a0[4] = (_Float16)v1.x; a0[5] = (_Float16)v1.y; a0[6] = (_Float16)v1.z; a0[7] = (_Float16)v1.w;
        a1[0] = (_Float16)v2.x; a1[1] = (_Float16)v2.y; a1[2] = (_Float16)v2.z; a1[3] = (_Float16)v2.w;
        a1[4] = (_Float16)v3.x; a1[5] = (_Float16)v3.y; a1[6] = (_Float16)v3.z; a1[7] = (_Float16)v3.w;

        f32x4 acc[3];
#pragma unroll
        for (int nt = 0; nt < 3; ++nt) {
            acc[nt] = f32x4{dbl[nt], dbl[nt], dbl[nt], dbl[nt]};
            acc[nt] = __builtin_amdgcn_mfma_f32_16x16x32_f16(a0, bf[0][nt], acc[nt], 0, 0, 0);
            acc[nt] = __builtin_amdgcn_mfma_f32_16x16x32_f16(a1, bf[1][nt], acc[nt], 0, 0, 0);
        }

#pragma unroll
        for (int r = 0; r < 4; ++r) {
            const float v0r = acc[0][r];
            const float v1r = acc[1][r];
            const float v2r = (lrow < 13) ? acc[2][r] : -INFINITY;
            float mxv = fmaxf(fmaxf(v0r, v1r), v2r);
#pragma unroll
            for (int s = 1; s < 16; s <<= 1) mxv = fmaxf(mxv, __shfl_xor(mxv, s, 64));
            const float e0 = __expf(v0r - mxv);
            const float e1 = __expf(v1r - mxv);
            const float e2 = (lrow < 13) ? __expf(acc[2][r] - mxv) : 0.f;
            float ssum = e0 + e1 + e2;
#pragma unroll
            for (int s = 1; s < 16; s <<= 1) ssum += __shfl_xor(ssum, s, 64);
            const float inv = 1.f / ssum;

            float* o = out + (size_t)(m0 + 4 * g + r) * C_;
            o[lrow]      = e0 * inv;
            o[16 + lrow] = e1 * inv;
            if (lrow < 13) o[32 + lrow] = e2 * inv;
        }
    }
}

// ---------------------------------------------------------------------------
// prep2: fragment-ready dense_w for the MFMA head (unchanged).
// ---------------------------------------------------------------------------
__global__ __launch_bounds__(256) void prep2_kernel(
    const float* __restrict__ dw,    // [64, 45]
    half_t* __restrict__ dwt)        // [2*3*64*8]
{
    const int idx = blockIdx.x * 256 + threadIdx.x;
    if (idx >= 2 * 3 * 64) return;
    const int l   = idx & 63;
    const int nt  = (idx >> 6) % 3;
    const int ks2 = idx / (64 * 3);
    const int col = nt * 16 + (l & 15);
    const int kb  = ks2 * 32 + (l >> 4) * 8;

    half_t v[8];
#pragma unroll
    for (int e = 0; e < 8; ++e) {
        const float f = (col < C_) ? dw[(size_t)(kb + e) * C_ + col] : 0.f;
        v[e] = (half_t)f;
    }
    *(f16x8*)(dwt + (size_t)idx * 8) = *(const f16x8*)v;
}

// ---------------------------------------------------------------------------
// FUSED proj+scan. Wave 0 = R10-structure scan with v_pk_fma_f32 dots:
//  - R kept in f32 as f32x2 pairs (192 VGPRs; occupancy is LDS-pinned at
//    1 block/CU so the large allocation is free -> __launch_bounds__(256,1)).
//  - 96 inline-asm v_pk_fma_f32 = half the issue slots of the 192 fma_mix.
//  - h broadcast in f32 LDS (256 B): 1 ds_write_b32 + 16 uniform ds_read_b128.
//  - no f16 quantization of R or h anymore (strictly more precise).
// Waves 1-3 = MFMA proj producing chunk c+1 into mxbuf (unchanged).
// ---------------------------------------------------------------------------
__global__ __launch_bounds__(256, 1) void fused_kernel(
    const float*  __restrict__ x,      // [B*T, 300]
    const half_t* __restrict__ wt_hi,
    const half_t* __restrict__ wt_lo,
    const float*  __restrict__ bias,   // [2, 192]
    const float*  __restrict__ rk,     // [64, 192]
    float* __restrict__ hs)            // [B, T, 64] f32
{
    __shared__ float mxbuf[2][64][192];           // 96 KB double buffer
    __shared__ __align__(16) float hb32[64];      // h broadcast (256 B, f32)
    const int tid = threadIdx.x;
    const int wv  = tid >> 6;
    const int l   = tid & 63;
    const int b   = blockIdx.x;

    if (wv == 0) {
        // ------------------- scan wave (pk_fma_f32, f32 R) ------------------
        const int j = l;
        f32x2 Rz[32], Rr[32], Rh[32];
#pragma unroll
        for (int p = 0; p < 32; ++p) {
            Rz[p] = f32x2{rk[(size_t)(2 * p) * 192 + j],       rk[(size_t)(2 * p + 1) * 192 + j]};
            Rr[p] = f32x2{rk[(size_t)(2 * p) * 192 + 64 + j],  rk[(size_t)(2 * p + 1) * 192 + 64 + j]};
            Rh[p] = f32x2{rk[(size_t)(2 * p) * 192 + 128 + j], rk[(size_t)(2 * p + 1) * 192 + 128 + j]};
        }
        const float rbz = bias[192 + j];
        const float rbr = bias[192 + 64 + j];
        const float rbh = bias[192 + 128 + j];

        hb32[j] = 0.f;
        float hj = 0.f;
        float* hsb = hs + (size_t)b * T_ * 64 + j;

        __syncthreads();                      // chunk 0 ready

        for (int c = 0; c < 8; ++c) {
            const float (*mb)[192] = mxbuf[c & 1];
            float z0 = mb[0][j], r0 = mb[0][64 + j], q0 = mb[0][128 + j];
            float z1 = mb[1][j], r1 = mb[1][64 + j], q1 = mb[1][128 + j];

            for (int tt = 0; tt < 64; tt += 2) {
#pragma unroll
                for (int i = 0; i < 2; ++i) {
                    const float xz = (i == 0) ? z0 : z1;
                    const float xr = (i == 0) ? r0 : r1;
                    const float xh = (i == 0) ? q0 : q1;
                    const int tp = (tt + 2 + i < 64) ? (tt + 2 + i) : 63;
                    const float zn = mb[tp][j];
                    const float rn = mb[tp][64 + j];
                    const float qn = mb[tp][128 + j];

                    // h broadcast: 16 uniform ds_read_b128 (64 f32 = 256 B)
                    const f32x4* h4p = (const f32x4*)hb32;
                    f32x2 az0 = {rbz, 0.f}, az1 = {0.f, 0.f};
                    f32x2 ar0 = {rbr, 0.f}, ar1 = {0.f, 0.f};
                    f32x2 ah0 = {rbh, 0.f}, ah1 = {0.f, 0.f};
#pragma unroll
                    for (int q = 0; q < 16; ++q) {
                        const f32x4 hv = h4p[q];
                        const f32x2 hA = {hv.x, hv.y};
                        const f32x2 hB = {hv.z, hv.w};
                        az0 = pkfma_(hA, Rz[2 * q], az0);
                        az1 = pkfma_(hB, Rz[2 * q + 1], az1);
                        ar0 = pkfma_(hA, Rr[2 * q], ar0);
                        ar1 = pkfma_(hB, Rr[2 * q + 1], ar1);
                        ah0 = pkfma_(hA, Rh[2 * q], ah0);
                        ah1 = pkfma_(hB, Rh[2 * q + 1], ah1);
                    }
                    const float miz = (az0.x + az1.x) + (az0.y + az1.y);
                    const float mir = (ar0.x + ar1.x) + (ar0.y + ar1.y);
                    const float mih = (ah0.x + ah1.x) + (ah0.y + ah1.y);

                    const float zg = FRCP(1.f + __expf(-(xz + miz)));
                    const float rg = FRCP(1.f + __expf(-(xr + mir)));
                    const float hh = fmaxf(fmaf(rg, mih, xh), 0.f);
                    const float hn = fmaf(zg, hj - hh, hh);

                    hb32[j] = hn;                                // ds_write_b32
                    hj = hn;
                    hsb[(size_t)(c * 64 + tt + i) * 64] = hn;    // f32 history

                    if (i == 0) { z0 = zn; r0 = rn; q0 = qn; }
                    else        { z1 = zn; r1 = rn; q1 = qn; }
                }
            }
            __syncthreads();                  // next chunk ready
        }
    } else {
        // ------------------------ proj waves (unchanged) -------------------
        const int pw   = wv - 1;              // 0..2: n-tiles pw*4 .. pw*4+3
        const int lrow = l & 15;
        const int g    = l >> 4;
        float b0[4];
#pragma unroll
        for (int q = 0; q < 4; ++q) b0[q] = bias[(pw * 4 + q) * 16 + lrow];

        auto produce = [&](int c) {
            const int t0 = c * 64;
            f32x4 acc[4][4];
#pragma unroll
            for (int mi = 0; mi < 4; ++mi)
#pragma unroll
                for (int q = 0; q < 4; ++q)
                    acc[mi][q] = f32x4{b0[q], b0[q], b0[q], b0[q]};

            for (int ks = 0; ks < KSTEPS; ++ks) {
                f16x8 bh[4], bl[4];
#pragma unroll
                for (int q = 0; q < 4; ++q) {
                    const size_t off = ((size_t)(ks * NTILES + pw * 4 + q) * 64 + l) * 8;
                    bh[q] = *(const f16x8*)(wt_hi + off);
                    bl[q] = *(const f16x8*)(wt_lo + off);
                }
#pragma unroll
                for (int mi = 0; mi < 4; ++mi) {
                    const float* xr = x + (size_t)(b * 512 + t0 + mi * 16 + lrow) * D_ + ks * 32 + g * 8;
                    float xv[8];
                    if (ks < 9) {
                        const float4 v0 = ((const float4*)xr)[0];
                        const float4 v1 = ((const float4*)xr)[1];
                        xv[0] = v0.x; xv[1] = v0.y; xv[2] = v0.z; xv[3] = v0.w;
                        xv[4] = v1.x; xv[5] = v1.y; xv[6] = v1.z; xv[7] = v1.w;
                    } else {
                        const int kb = 288 + g * 8;
#pragma unroll
                        for (int e = 0; e < 8; ++e) xv[e] = (kb + e < D_) ? xr[e] : 0.f;
                    }
                    f16x8 ahi, alo;
#pragma unroll
                    for (int e = 0; e < 8; ++e) {
                        const half_t h = (half_t)xv[e];
                        ahi[e] = h;
                        alo[e] = (half_t)(xv[e] - (float)h);
                    }
#pragma unroll
                    for (int q = 0; q < 4; ++q) {
                        acc[mi][q] = __builtin_amdgcn_mfma_f32_16x16x32_f16(ahi, bh[q], acc[mi][q], 0, 0, 0);
                        acc[mi][q] = __builtin_amdgcn_mfma_f32_16x16x32_f16(alo, bh[q], acc[mi][q], 0, 0, 0);
                        acc[mi][q] = __builtin_amdgcn_mfma_f32_16x16x32_f16(ahi, bl[q], acc[mi][q], 0, 0, 0);
                    }
                }
            }
            const int cb = c & 1;
#pragma unroll
            for (int mi = 0; mi < 4; ++mi)
#pragma unroll
                for (int q = 0; q < 4; ++q) {
                    const int col = (pw * 4 + q) * 16 + lrow;
#pragma unroll
                    for (int r = 0; r < 4; ++r)
                        mxbuf[cb][mi * 16 + 4 * g + r][col] = acc[mi][q][r];
                }
        };

        produce(0);
        __syncthreads();
        for (int c = 0; c < 8; ++c) {
            if (c < 7) produce(c + 1);
            __syncthreads();
        }
    }
}

// ---------------------------------------------------------------------------
extern "C" void kernel_launch(void* const* d_in, const int* in_sizes, int n_in,
                              void* d_out, int out_size, void* d_ws, size_t ws_size,
                              hipStream_t stream) {
    const float* x  = (const float*)d_in[0];
    const float* w  = (const float*)d_in[1];
    const float* rk = (const float*)d_in[2];
    const float* bs = (const float*)d_in[3];
    const float* dw = (const float*)d_in[4];
    const float* db = (const float*)d_in[5];
    float* out = (float*)d_out;

    char* ws = (char*)d_ws;
    float*  hs    = (float*)(ws + (size_t)131072 * 192 * 4);      //  33.55 MB
    half_t* wt_hi = (half_t*)(ws + (size_t)131072 * 256 * 4);     // 122,880 B
    half_t* wt_lo = wt_hi + (size_t)KSTEPS * NTILES * 64 * 8;     // 122,880 B
    half_t* dwt   = wt_lo + (size_t)KSTEPS * NTILES * 64 * 8;     //   6,144 B

    prep_kernel <<<30,   256, 0, stream>>>(w, wt_hi, wt_lo);
    prep2_kernel<<<2,    256, 0, stream>>>(dw, dwt);
    fused_kernel<<<256,  256, 0, stream>>>(x, wt_hi, wt_lo, bs, rk, hs);
    head_kernel <<<1024, 256, 0, stream>>>(hs, dwt, db, out);
}

// Round 14
// 196.304 us; speedup vs baseline: 1.9982x; 1.9982x over previous
//
#include <hip/hip_runtime.h>
#include <math.h>

#define B_ 256
#define T_ 512
#define D_ 300
#define U_ 64
#define C_ 45

typedef _Float16 half_t;
typedef __attribute__((ext_vector_type(2))) _Float16 f16x2;
typedef __attribute__((ext_vector_type(8))) _Float16 f16x8;
typedef __attribute__((ext_vector_type(4))) float f32x4;

// K padded 300 -> 320 (10 MFMA K-steps of 32). 12 N-tiles of 16 cols (192).
#define KSTEPS 10
#define NTILES 12

#if __has_builtin(__builtin_amdgcn_rcpf)
#define FRCP(x) __builtin_amdgcn_rcpf(x)
#else
#define FRCP(x) (1.0f / (x))
#endif

static __device__ inline float fdot2_(f16x2 a, f16x2 b, float c) {
#if __has_builtin(__builtin_amdgcn_fdot2)
    return __builtin_amdgcn_fdot2(a, b, c, false);   // v_dot2_f32_f16
#else
    return fmaf((float)a.x, (float)b.x, fmaf((float)a.y, (float)b.y, c));
#endif
}

// ---------------------------------------------------------------------------
// prep: build fragment-ready transposed w in fp16 hi/lo split (unchanged).
// ---------------------------------------------------------------------------
__global__ __launch_bounds__(256) void prep_kernel(
    const float* __restrict__ w,     // [300, 192]
    half_t* __restrict__ wt_hi,      // [7680*8]
    half_t* __restrict__ wt_lo)      // [7680*8]
{
    const int idx = blockIdx.x * 256 + threadIdx.x;
    if (idx >= KSTEPS * NTILES * 64) return;
    const int l  = idx & 63;
    const int nt = (idx >> 6) % NTILES;
    const int ks = idx / (64 * NTILES);
    const int col   = nt * 16 + (l & 15);
    const int kbase = ks * 32 + (l >> 4) * 8;

    half_t hi[8], lo[8];
#pragma unroll
    for (int e = 0; e < 8; ++e) {
        const int k = kbase + e;
        const float v = (k < D_) ? w[(size_t)k * 192 + col] : 0.f;
        const half_t h = (half_t)v;
        hi[e] = h;
        lo[e] = (half_t)(v - (float)h);
    }
    *(f16x8*)(wt_hi + (size_t)idx * 8) = *(const f16x8*)hi;
    *(f16x8*)(wt_lo + (size_t)idx * 8) = *(const f16x8*)lo;
}

// ---------------------------------------------------------------------------
// Kernel 1 (retained, no longer launched): MFMA projection — context anchor.
// ---------------------------------------------------------------------------
__global__ __launch_bounds__(256, 4) void proj_kernel(
    const float*  __restrict__ x,      // [M, 300]
    const half_t* __restrict__ wt_hi,
    const half_t* __restrict__ wt_lo,
    const float*  __restrict__ bias,   // [2, 192], row 0 = input bias
    float* __restrict__ mx)            // [M, 192]
{
    const int tid  = threadIdx.x;
    const int l    = tid & 63;
    const int wv   = tid >> 6;          // 0..3
    const int lrow = l & 15;
    const int g    = l >> 4;            // 0..3 (k-group)
    const int m0   = blockIdx.x * 64;

    f32x4 acc[4][3];
#pragma unroll
    for (int ni = 0; ni < 3; ++ni) {
        const float b = bias[wv * 48 + ni * 16 + lrow];
        const f32x4 bv = {b, b, b, b};
#pragma unroll
        for (int mi = 0; mi < 4; ++mi) acc[mi][ni] = bv;
    }

    for (int ks = 0; ks < KSTEPS; ++ks) {
        f16x8 bhi[3], blo[3];
#pragma unroll
        for (int ni = 0; ni < 3; ++ni) {
            const size_t off = ((size_t)(ks * NTILES + wv * 3 + ni) * 64 + l) * 8;
            bhi[ni] = *(const f16x8*)(wt_hi + off);
            blo[ni] = *(const f16x8*)(wt_lo + off);
        }
#pragma unroll
        for (int mi = 0; mi < 4; ++mi) {
            const float* xr = x + (size_t)(m0 + mi * 16 + lrow) * D_ + ks * 32 + g * 8;
            float xv[8];
            if (ks < 9) {
                const float4 v0 = ((const float4*)xr)[0];
                const float4 v1 = ((const float4*)xr)[1];
                xv[0] = v0.x; xv[1] = v0.y; xv[2] = v0.z; xv[3] = v0.w;
                xv[4] = v1.x; xv[5] = v1.y; xv[6] = v1.z; xv[7] = v1.w;
            } else {
                const int kb = 288 + g * 8;   // predicated tail (k in [288,320))
#pragma unroll
                for (int e = 0; e < 8; ++e) xv[e] = (kb + e < D_) ? xr[e] : 0.f;
            }
            f16x8 ahi, alo;
#pragma unroll
            for (int e = 0; e < 8; ++e) {
                const half_t h = (half_t)xv[e];
                ahi[e] = h;
                alo[e] = (half_t)(xv[e] - (float)h);
            }
#pragma unroll
            for (int ni = 0; ni < 3; ++ni) {
                acc[mi][ni] = __builtin_amdgcn_mfma_f32_16x16x32_f16(ahi, bhi[ni], acc[mi][ni], 0, 0, 0);
                acc[mi][ni] = __builtin_amdgcn_mfma_f32_16x16x32_f16(alo, bhi[ni], acc[mi][ni], 0, 0, 0);
                acc[mi][ni] = __builtin_amdgcn_mfma_f32_16x16x32_f16(ahi, blo[ni], acc[mi][ni], 0, 0, 0);
            }
        }
    }

#pragma unroll
    for (int mi = 0; mi < 4; ++mi) {
        const int rbase = m0 + mi * 16 + g * 4;
#pragma unroll
        for (int ni = 0; ni < 3; ++ni) {
            const int col = wv * 48 + ni * 16 + lrow;
#pragma unroll
            for (int r = 0; r < 4; ++r)
                mx[(size_t)(rbase + r) * 192 + col] = acc[mi][ni][r];
        }
    }
}

// ---------------------------------------------------------------------------
// Kernel 2 (retained, no longer launched): R5 scan — context anchor.
// ---------------------------------------------------------------------------
__global__ __launch_bounds__(64) void scan_kernel(
    const float* __restrict__ mx,    // [B, T, 192]
    const float* __restrict__ rk,    // [64, 192]
    const float* __restrict__ bias,  // [2, 192], row 1 = recurrent bias
    float* __restrict__ hs)          // [B, T, 64]
{
    __shared__ _Float16 hbuf[64];    // 128 B
    const int j = threadIdx.x;       // 0..63
    const int b = blockIdx.x;

    f16x2 Rz[32], Rr[32], Rh[32];
#pragma unroll
    for (int p = 0; p < 32; ++p) {
        Rz[p] = f16x2{(_Float16)rk[(size_t)(2 * p) * 192 + j],
                      (_Float16)rk[(size_t)(2 * p + 1) * 192 + j]};
        Rr[p] = f16x2{(_Float16)rk[(size_t)(2 * p) * 192 + 64 + j],
                      (_Float16)rk[(size_t)(2 * p + 1) * 192 + 64 + j]};
        Rh[p] = f16x2{(_Float16)rk[(size_t)(2 * p) * 192 + 128 + j],
                      (_Float16)rk[(size_t)(2 * p + 1) * 192 + 128 + j]};
    }
    const float rbz = bias[192 + j];
    const float rbr = bias[192 + 64 + j];
    const float rbh = bias[192 + 128 + j];

    hbuf[j] = (_Float16)0.f;
    float hj = 0.f;

    const float* mxb = mx + (size_t)b * T_ * 192 + j;
    float* hsb = hs + (size_t)b * T_ * 64 + j;

    float zb[4], rbv[4], qb[4];
#pragma unroll
    for (int i = 0; i < 4; ++i) {
        const float* p = mxb + (size_t)i * 192;
        zb[i] = p[0]; rbv[i] = p[64]; qb[i] = p[128];
    }

    union H8 { f16x8 v; f16x2 p[4]; };

    for (int t0 = 0; t0 < T_; t0 += 4) {
#pragma unroll
        for (int i = 0; i < 4; ++i) {
            const int t = t0 + i;
            const float xz = zb[i], xr = rbv[i], xh = qb[i];
            {
                const int tp = (t + 4 < T_) ? (t + 4) : (T_ - 1);
                const float* pf = mxb + (size_t)tp * 192;
                zb[i] = pf[0]; rbv[i] = pf[64]; qb[i] = pf[128];
            }
            H8 hv[8];
            const f16x8* h8 = (const f16x8*)hbuf;
#pragma unroll
            for (int q = 0; q < 8; ++q) hv[q].v = h8[q];

            float az[4] = {rbz, 0.f, 0.f, 0.f};
            float ar[4] = {rbr, 0.f, 0.f, 0.f};
            float ah[4] = {rbh, 0.f, 0.f, 0.f};
#pragma unroll
            for (int p = 0; p < 32; ++p) {
                const f16x2 hp = hv[p >> 2].p[p & 3];
                az[p & 3] = fdot2_(hp, Rz[p], az[p & 3]);
                ar[p & 3] = fdot2_(hp, Rr[p], ar[p & 3]);
                ah[p & 3] = fdot2_(hp, Rh[p], ah[p & 3]);
            }
            const float miz = (az[0] + az[1]) + (az[2] + az[3]);
            const float mir = (ar[0] + ar[1]) + (ar[2] + ar[3]);
            const float mih = (ah[0] + ah[1]) + (ah[2] + ah[3]);

            const float zg = FRCP(1.f + __expf(-(xz + miz)));
            const float rg = FRCP(1.f + __expf(-(xr + mir)));
            const float hh = fmaxf(fmaf(rg, mih, xh), 0.f);
            const float hn = fmaf(zg, hj - hh, hh);

            hbuf[j] = (_Float16)hn;
            hj = hn;
            hsb[(size_t)t * 64] = hn;
        }
    }
}

// ---------------------------------------------------------------------------
// Kernel 3: MFMA head reading f32 hs (unchanged).
// ---------------------------------------------------------------------------
__global__ __launch_bounds__(256) void head_kernel(
    const float* __restrict__ hs,     // [M, 64] f32
    const half_t* __restrict__ dwt,   // [2][3][64][8] f16 frags
    const float* __restrict__ db,     // [45]
    float* __restrict__ out)          // [M, 45]
{
    const int l    = threadIdx.x & 63;
    const int wv   = threadIdx.x >> 6;
    const int lrow = l & 15;
    const int g    = l >> 4;

    f16x8 bf[2][3];
#pragma unroll
    for (int ks2 = 0; ks2 < 2; ++ks2)
#pragma unroll
        for (int nt = 0; nt < 3; ++nt)
            bf[ks2][nt] = *(const f16x8*)(dwt + (size_t)((ks2 * 3 + nt) * 64 + l) * 8);
    float dbl[3];
#pragma unroll
    for (int nt = 0; nt < 3; ++nt) {
        const int col = nt * 16 + lrow;
        dbl[nt] = (col < C_) ? db[col] : 0.f;
    }

    const int gw = blockIdx.x * 4 + wv;
    const int nw = gridDim.x * 4;
    const int NTILE_M = (B_ * T_) / 16;   // 8192
    for (int tile = gw; tile < NTILE_M; tile += nw) {
        const int m0 = tile * 16;
        const float* ar = hs + (size_t)(m0 + lrow) * 64 + g * 8;
        const float4 v0 = ((const float4*)ar)[0];
        const float4 v1 = ((const float4*)ar)[1];
        const float4 v2 = ((const float4*)(ar + 32))[0];
        const float4 v3 = ((const float4*)(ar + 32))[1];
        f16x8 a0, a1;
        a0[0] = (_Float16)v0.x; a0[1] = (_Float16)v0.y; a0[2] = (_Float16)v0.z; a0[3] = (_Float16)v0.w;
        a0[4] = (_Float16)v1.x; a0[5] = (_Float16)v1.y; a0[6] = (_Float16)v1.z; a0[7] = (_Float16)v1.w;
        a1[0] = (_Float16)v2.x; a1[1] = (_Float16)v2.y; a1[2] = (_Float16)v2.z; a1[3] = (_Float16)v2.w;
        a1[4] = (_Float16)v3.x; a1[5] = (_Float16)v3.y; a1[6] = (_Float16)v3.z; a1[7] = (_Float16)v3.w;

        f32x4 acc[3];
#pragma unroll
        for (int nt = 0; nt < 3; ++nt) {
            acc[nt] = f32x4{dbl[nt], dbl[nt], dbl[nt], dbl[nt]};
            acc[nt] = __builtin_amdgcn_mfma_f32_16x16x32_f16(a0, bf[0][nt], acc[nt], 0, 0, 0);
            acc[nt] = __builtin_amdgcn_mfma_f32_16x16x32_f16(a1, bf[1][nt], acc[nt], 0, 0, 0);
        }

#pragma unroll
        for (int r = 0; r < 4; ++r) {
            const float v0r = acc[0][r];
            const float v1r = acc[1][r];
            const float v2r = (lrow < 13) ? acc[2][r] : -INFINITY;
            float mxv = fmaxf(fmaxf(v0r, v1r), v2r);
#pragma unroll
            for (int s = 1; s < 16; s <<= 1) mxv = fmaxf(mxv, __shfl_xor(mxv, s, 64));
            const float e0 = __expf(v0r - mxv);
            const float e1 = __expf(v1r - mxv);
            const float e2 = (lrow < 13) ? __expf(acc[2][r] - mxv) : 0.f;
            float ssum = e0 + e1 + e2;
#pragma unroll
            for (int s = 1; s < 16; s <<= 1) ssum += __shfl_xor(ssum, s, 64);
            const float inv = 1.f / ssum;

            float* o = out + (size_t)(m0 + 4 * g + r) * C_;
            o[lrow]      = e0 * inv;
            o[16 + lrow] = e1 * inv;
            if (lrow < 13) o[32 + lrow] = e2 * inv;
        }
    }
}

// ---------------------------------------------------------------------------
// prep2: fragment-ready dense_w for the MFMA head (unchanged).
// ---------------------------------------------------------------------------
__global__ __launch_bounds__(256) void prep2_kernel(
    const float* __restrict__ dw,    // [64, 45]
    half_t* __restrict__ dwt)        // [2*3*64*8]
{
    const int idx = blockIdx.x * 256 + threadIdx.x;
    if (idx >= 2 * 3 * 64) return;
    const int l   = idx & 63;
    const int nt  = (idx >> 6) % 3;
    const int ks2 = idx / (64 * 3);
    const int col = nt * 16 + (l & 15);
    const int kb  = ks2 * 32 + (l >> 4) * 8;

    half_t v[8];
#pragma unroll
    for (int e = 0; e < 8; ++e) {
        const float f = (col < C_) ? dw[(size_t)(kb + e) * C_ + col] : 0.f;
        v[e] = (half_t)f;
    }
    *(f16x8*)(dwt + (size_t)idx * 8) = *(const f16x8*)v;
}

// ---------------------------------------------------------------------------
// FUSED proj+scan: 256 blocks (one per batch) x 256 threads.
// Wave 0 = R5-exact GRU scan reading mx from an LDS double buffer.
// Waves 1-3 = MFMA projection producing chunk c+1 (64 timesteps of mx for
// this batch) while wave 0 scans chunk c. Waves sit on different SIMDs ->
// no issue contention. __syncthreads() only at the 8 chunk boundaries.
// mx never touches HBM. MFMA ordering identical to proj_kernel -> mx
// bit-exact; scan math identical to scan_kernel -> absmax invariant.
// ---------------------------------------------------------------------------
__global__ __launch_bounds__(256) void fused_kernel(
    const float*  __restrict__ x,      // [B*T, 300]
    const half_t* __restrict__ wt_hi,
    const half_t* __restrict__ wt_lo,
    const float*  __restrict__ bias,   // [2, 192]
    const float*  __restrict__ rk,     // [64, 192]
    float* __restrict__ hs)            // [B, T, 64] f32
{
    __shared__ float mxbuf[2][64][192];   // 96 KB double buffer
    __shared__ _Float16 hbuf[64];
    const int tid = threadIdx.x;
    const int wv  = tid >> 6;
    const int l   = tid & 63;
    const int b   = blockIdx.x;

    if (wv == 0) {
        // ------------------------- scan wave -------------------------
        const int j = l;
        f16x2 Rz[32], Rr[32], Rh[32];
#pragma unroll
        for (int p = 0; p < 32; ++p) {
            Rz[p] = f16x2{(_Float16)rk[(size_t)(2 * p) * 192 + j],
                          (_Float16)rk[(size_t)(2 * p + 1) * 192 + j]};
            Rr[p] = f16x2{(_Float16)rk[(size_t)(2 * p) * 192 + 64 + j],
                          (_Float16)rk[(size_t)(2 * p + 1) * 192 + 64 + j]};
            Rh[p] = f16x2{(_Float16)rk[(size_t)(2 * p) * 192 + 128 + j],
                          (_Float16)rk[(size_t)(2 * p + 1) * 192 + 128 + j]};
        }
        const float rbz = bias[192 + j];
        const float rbr = bias[192 + 64 + j];
        const float rbh = bias[192 + 128 + j];

        hbuf[j] = (_Float16)0.f;
        float hj = 0.f;
        float* hsb = hs + (size_t)b * T_ * 64 + j;

        union H8 { f16x8 v; f16x2 p[4]; };
        __syncthreads();                      // chunk 0 ready

        for (int c = 0; c < 8; ++c) {
            const float (*mb)[192] = mxbuf[c & 1];
            // prime two slots (steps 0,1 of the chunk)
            float z0 = mb[0][j], r0 = mb[0][64 + j], q0 = mb[0][128 + j];
            float z1 = mb[1][j], r1 = mb[1][64 + j], q1 = mb[1][128 + j];

            for (int tt = 0; tt < 64; tt += 2) {
#pragma unroll
                for (int i = 0; i < 2; ++i) {
                    const float xz = (i == 0) ? z0 : z1;
                    const float xr = (i == 0) ? r0 : r1;
                    const float xh = (i == 0) ? q0 : q1;
                    // prefetch 2 steps ahead within the chunk (clamped)
                    const int tp = (tt + 2 + i < 64) ? (tt + 2 + i) : 63;
                    const float zn = mb[tp][j];
                    const float rn = mb[tp][64 + j];
                    const float qn = mb[tp][128 + j];

                    H8 hv[8];
                    const f16x8* h8 = (const f16x8*)hbuf;
#pragma unroll
                    for (int q = 0; q < 8; ++q) hv[q].v = h8[q];

                    float az[4] = {rbz, 0.f, 0.f, 0.f};
                    float ar[4] = {rbr, 0.f, 0.f, 0.f};
                    float ah[4] = {rbh, 0.f, 0.f, 0.f};
#pragma unroll
                    for (int p = 0; p < 32; ++p) {
                        const f16x2 hp = hv[p >> 2].p[p & 3];
                        az[p & 3] = fdot2_(hp, Rz[p], az[p & 3]);
                        ar[p & 3] = fdot2_(hp, Rr[p], ar[p & 3]);
                        ah[p & 3] = fdot2_(hp, Rh[p], ah[p & 3]);
                    }
                    const float miz = (az[0] + az[1]) + (az[2] + az[3]);
                    const float mir = (ar[0] + ar[1]) + (ar[2] + ar[3]);
                    const float mih = (ah[0] + ah[1]) + (ah[2] + ah[3]);

                    const float zg = FRCP(1.f + __expf(-(xz + miz)));
                    const float rg = FRCP(1.f + __expf(-(xr + mir)));
                    const float hh = fmaxf(fmaf(rg, mih, xh), 0.f);
                    const float hn = fmaf(zg, hj - hh, hh);

                    hbuf[j] = (_Float16)hn;
                    hj = hn;
                    hsb[(size_t)(c * 64 + tt + i) * 64] = hn;

                    if (i == 0) { z0 = zn; r0 = rn; q0 = qn; }
                    else        { z1 = zn; r1 = rn; q1 = qn; }
                }
            }
            __syncthreads();                  // next chunk ready
        }
    } else {
        // ------------------------ proj waves -------------------------
        const int pw   = wv - 1;              // 0..2: n-tiles pw*4 .. pw*4+3
        const int lrow = l & 15;
        const int g    = l >> 4;
        float b0[4];
#pragma unroll
        for (int q = 0; q < 4; ++q) b0[q] = bias[(pw * 4 + q) * 16 + lrow];

        auto produce = [&](int c) {
            const int t0 = c * 64;
            f32x4 acc[4][4];
#pragma unroll
            for (int mi = 0; mi < 4; ++mi)
#pragma unroll
                for (int q = 0; q < 4; ++q)
                    acc[mi][q] = f32x4{b0[q], b0[q], b0[q], b0[q]};

            for (int ks = 0; ks < KSTEPS; ++ks) {
                f16x8 bh[4], bl[4];
#pragma unroll
                for (int q = 0; q < 4; ++q) {
                    const size_t off = ((size_t)(ks * NTILES + pw * 4 + q) * 64 + l) * 8;
                    bh[q] = *(const f16x8*)(wt_hi + off);
                    bl[q] = *(const f16x8*)(wt_lo + off);
                }
#pragma unroll
                for (int mi = 0; mi < 4; ++mi) {
                    const float* xr = x + (size_t)(b * 512 + t0 + mi * 16 + lrow) * D_ + ks * 32 + g * 8;
                    float xv[8];
                    if (ks < 9) {
                        const float4 v0 = ((const float4*)xr)[0];
                        const float4 v1 = ((const float4*)xr)[1];
                        xv[0] = v0.x; xv[1] = v0.y; xv[2] = v0.z; xv[3] = v0.w;
                        xv[4] = v1.x; xv[5] = v1.y; xv[6] = v1.z; xv[7] = v1.w;
                    } else {
                        const int kb = 288 + g * 8;
#pragma unroll
                        for (int e = 0; e < 8; ++e) xv[e] = (kb + e < D_) ? xr[e] : 0.f;
                    }
                    f16x8 ahi, alo;
#pragma unroll
                    for (int e = 0; e < 8; ++e) {
                        const half_t h = (half_t)xv[e];
                        ahi[e] = h;
                        alo[e] = (half_t)(xv[e] - (float)h);
                    }
#pragma unroll
                    for (int q = 0; q < 4; ++q) {
                        acc[mi][q] = __builtin_amdgcn_mfma_f32_16x16x32_f16(ahi, bh[q], acc[mi][q], 0, 0, 0);
                        acc[mi][q] = __builtin_amdgcn_mfma_f32_16x16x32_f16(alo, bh[q], acc[mi][q], 0, 0, 0);
                        acc[mi][q] = __builtin_amdgcn_mfma_f32_16x16x32_f16(ahi, bl[q], acc[mi][q], 0, 0, 0);
                    }
                }
            }
            // D-frag -> LDS: row = mi*16 + 4*g + r (t within chunk), col
            const int cb = c & 1;
#pragma unroll
            for (int mi = 0; mi < 4; ++mi)
#pragma unroll
                for (int q = 0; q < 4; ++q) {
                    const int col = (pw * 4 + q) * 16 + lrow;
#pragma unroll
                    for (int r = 0; r < 4; ++r)
                        mxbuf[cb][mi * 16 + 4 * g + r][col] = acc[mi][q][r];
                }
        };

        produce(0);
        __syncthreads();
        for (int c = 0; c < 8; ++c) {
            if (c < 7) produce(c + 1);
            __syncthreads();
        }
    }
}

// ---------------------------------------------------------------------------
extern "C" void kernel_launch(void* const* d_in, const int* in_sizes, int n_in,
                              void* d_out, int out_size, void* d_ws, size_t ws_size,
                              hipStream_t stream) {
    const float* x  = (const float*)d_in[0];
    const float* w  = (const float*)d_in[1];
    const float* rk = (const float*)d_in[2];
    const float* bs = (const float*)d_in[3];
    const float* dw = (const float*)d_in[4];
    const float* db = (const float*)d_in[5];
    float* out = (float*)d_out;

    char* ws = (char*)d_ws;
    float*  hs    = (float*)(ws + (size_t)131072 * 192 * 4);      //  33.55 MB
    half_t* wt_hi = (half_t*)(ws + (size_t)131072 * 256 * 4);     // 122,880 B
    half_t* wt_lo = wt_hi + (size_t)KSTEPS * NTILES * 64 * 8;     // 122,880 B
    half_t* dwt   = wt_lo + (size_t)KSTEPS * NTILES * 64 * 8;     //   6,144 B

    prep_kernel <<<30,   256, 0, stream>>>(w, wt_hi, wt_lo);
    prep2_kernel<<<2,    256, 0, stream>>>(dw, dwt);
    fused_kernel<<<256,  256, 0, stream>>>(x, wt_hi, wt_lo, bs, rk, hs);
    head_kernel <<<1024, 256, 0, stream>>>(hs, dwt, db, out);
}